// Round 6
// baseline (24.537 us; speedup 1.0000x reference)
//
#include <hip/hip_runtime.h>

#define N_SEQS 2048
#define SEQ_LEN 512
#define NAA 20
#define NS 21                 // states incl. gap (pad bin)
#define MPOS 100
#define G 5                   // tile side (positions)
#define NG 20                 // MPOS / G
#define NTILE 210             // NG*(NG+1)/2 tile-pairs (ti<=tj)
#define HB (NS * NS)          // 441
#define POSB 64               // pos blocks (8 positions each)

// ---------------------------------------------------------------------------
// Dispatch 1: per-position work + coalesced pack of columns 0..99.
// Block b handles positions i0=8b..8b+7: MI-row zeroing, pssm, conservation,
// and byte-pack cols[(i0+c)*2048 + s] (contiguous in s -> coalesced).
// ---------------------------------------------------------------------------
__global__ __launch_bounds__(256) void pos_kernel(const int* __restrict__ msa,
                                                  const float* __restrict__ pc,
                                                  unsigned char* __restrict__ cols,
                                                  int do_pack,
                                                  float* __restrict__ pssm,
                                                  float* __restrict__ cons,
                                                  float* __restrict__ mi) {
    __shared__ int ph[4][8 * NS];     // per-wave 8x21 histograms
    __shared__ float cntf[8 * NAA];
    const int tid = threadIdx.x;
    const int w = tid >> 6;
    const int i0 = blockIdx.x * 8;

    // zero MI rows i0..i0+7 (race-free split: MI blocks own off-diag [0,100)^2)
    for (int r = 0; r < 8; ++r) {
        const int i = i0 + r;
        float* rowp = mi + (size_t)i * SEQ_LEN;
        if (i < MPOS) {
            for (int c = MPOS + tid; c < SEQ_LEN; c += 256) rowp[c] = 0.f;
            if (tid == 0) rowp[i] = 0.f;
        } else {
            if (tid < SEQ_LEN / 4)
                ((float4*)rowp)[tid] = make_float4(0.f, 0.f, 0.f, 0.f);
        }
    }

    for (int k = tid; k < 4 * 8 * NS; k += 256) ((int*)ph)[k] = 0;
    __syncthreads();

    int* h = ph[w];
#pragma unroll
    for (int k = 0; k < 8; ++k) {
        const int s = tid + (k << 8);
        const int* rp = msa + (size_t)s * SEQ_LEN + i0;
        const int4 v0 = *(const int4*)rp;
        const int4 v1 = *(const int4*)(rp + 4);
        if (do_pack && i0 < MPOS) {
            if (i0 + 0 < MPOS) cols[(size_t)(i0 + 0) * N_SEQS + s] = (unsigned char)v0.x;
            if (i0 + 1 < MPOS) cols[(size_t)(i0 + 1) * N_SEQS + s] = (unsigned char)v0.y;
            if (i0 + 2 < MPOS) cols[(size_t)(i0 + 2) * N_SEQS + s] = (unsigned char)v0.z;
            if (i0 + 3 < MPOS) cols[(size_t)(i0 + 3) * N_SEQS + s] = (unsigned char)v0.w;
            if (i0 + 4 < MPOS) cols[(size_t)(i0 + 4) * N_SEQS + s] = (unsigned char)v1.x;
            if (i0 + 5 < MPOS) cols[(size_t)(i0 + 5) * N_SEQS + s] = (unsigned char)v1.y;
            if (i0 + 6 < MPOS) cols[(size_t)(i0 + 6) * N_SEQS + s] = (unsigned char)v1.z;
            if (i0 + 7 < MPOS) cols[(size_t)(i0 + 7) * N_SEQS + s] = (unsigned char)v1.w;
        }
        atomicAdd(&h[0 * NS + v0.x], 1);
        atomicAdd(&h[1 * NS + v0.y], 1);
        atomicAdd(&h[2 * NS + v0.z], 1);
        atomicAdd(&h[3 * NS + v0.w], 1);
        atomicAdd(&h[4 * NS + v1.x], 1);
        atomicAdd(&h[5 * NS + v1.y], 1);
        atomicAdd(&h[6 * NS + v1.z], 1);
        atomicAdd(&h[7 * NS + v1.w], 1);
    }
    __syncthreads();

    if (tid < 8 * NAA) {
        const int p = tid / NAA, a = tid - p * NAA;
        const int idx = p * NS + a;
        const int c = ph[0][idx] + ph[1][idx] + ph[2][idx] + ph[3][idx];
        cntf[tid] = (float)c;
        const float pcnt = 0.01f * pc[0];
        const float freq = __fdividef((float)c + pcnt, 2048.0f + pcnt * 20.0f);
        pssm[(size_t)(i0 + p) * NAA + a] = __logf(freq * 20.0f + 1e-10f);
    }
    __syncthreads();

    // conservation: 8 groups of 32 threads
    const int p = tid >> 5, l = tid & 31;
    const float fc = (l < NAA) ? cntf[p * NAA + l] : 0.f;
    float tt = fc;
#pragma unroll
    for (int o = 16; o; o >>= 1) tt += __shfl_xor(tt, o, 32);
    const float ts2 = fmaxf(tt, 1.f);
    const float f = __fdividef(fc, ts2);
    float term = (l < NAA) ? -f * __log2f(f + 1e-10f) : 0.f;
#pragma unroll
    for (int o = 16; o; o >>= 1) term += __shfl_xor(term, o, 32);
    if (l == 0)
        cons[i0 + p] = (tt > 0.f) ? (1.f - term * 0.2313782131597592f) : 0.f;
}

// ---------------------------------------------------------------------------
// Dispatch 2: MI over 5x5 position tiles, one tile-pair per block (210 blocks
// <= 256 CUs -> one heavy block per CU). 25 LDS histograms (44.1 KB).
// Finish uses MI = (Sum J lgJ - Sum Ra lgRa - Sum Cb lgCb)/T + lgT.
// ---------------------------------------------------------------------------
__global__ __launch_bounds__(256) void mi_kernel(const int* __restrict__ msa,
                                                 const unsigned char* __restrict__ cols,
                                                 int use_pack,
                                                 float* __restrict__ mi) {
    __shared__ int h_s[G * G * HB];   // 25*441*4 = 44100 B
    const int tid = threadIdx.x;
    const int w = tid >> 6;
    const int lane = tid & 63;

    int t = blockIdx.x, ti = 0, off = 0;
    while (off + (NG - ti) <= t) { off += NG - ti; ++ti; }
    const int tj = ti + (t - off);
    const int i0 = ti * G, j0 = tj * G;
    const bool diag = (ti == tj);

    for (int k = tid; k < G * G * HB; k += 256) h_s[k] = 0;
    __syncthreads();

    if (use_pack) {
#pragma unroll
        for (int pass = 0; pass < 2; ++pass) {
            const int s4 = pass * 1024 + tid * 4;   // 4 seqs per thread per pass
            const unsigned int ua0 = *(const unsigned int*)(cols + (size_t)(i0 + 0) * N_SEQS + s4);
            const unsigned int ua1 = *(const unsigned int*)(cols + (size_t)(i0 + 1) * N_SEQS + s4);
            const unsigned int ua2 = *(const unsigned int*)(cols + (size_t)(i0 + 2) * N_SEQS + s4);
            const unsigned int ua3 = *(const unsigned int*)(cols + (size_t)(i0 + 3) * N_SEQS + s4);
            const unsigned int ua4 = *(const unsigned int*)(cols + (size_t)(i0 + 4) * N_SEQS + s4);
            const unsigned int ub0 = *(const unsigned int*)(cols + (size_t)(j0 + 0) * N_SEQS + s4);
            const unsigned int ub1 = *(const unsigned int*)(cols + (size_t)(j0 + 1) * N_SEQS + s4);
            const unsigned int ub2 = *(const unsigned int*)(cols + (size_t)(j0 + 2) * N_SEQS + s4);
            const unsigned int ub3 = *(const unsigned int*)(cols + (size_t)(j0 + 3) * N_SEQS + s4);
            const unsigned int ub4 = *(const unsigned int*)(cols + (size_t)(j0 + 4) * N_SEQS + s4);
#pragma unroll
            for (int q = 0; q < 4; ++q) {
                const int sh = 8 * q;
                const int A0 = (int)((ua0 >> sh) & 0xFF) * NS;
                const int A1 = (int)((ua1 >> sh) & 0xFF) * NS;
                const int A2 = (int)((ua2 >> sh) & 0xFF) * NS;
                const int A3 = (int)((ua3 >> sh) & 0xFF) * NS;
                const int A4 = (int)((ua4 >> sh) & 0xFF) * NS;
                const int B0 = (int)((ub0 >> sh) & 0xFF);
                const int B1 = (int)((ub1 >> sh) & 0xFF);
                const int B2 = (int)((ub2 >> sh) & 0xFF);
                const int B3 = (int)((ub3 >> sh) & 0xFF);
                const int B4 = (int)((ub4 >> sh) & 0xFF);
#define UPD(PI, PJ, AA, BB) atomicAdd(&h_s[(PI * G + PJ) * HB + AA + BB], 1)
                UPD(0, 0, A0, B0); UPD(0, 1, A0, B1); UPD(0, 2, A0, B2); UPD(0, 3, A0, B3); UPD(0, 4, A0, B4);
                UPD(1, 0, A1, B0); UPD(1, 1, A1, B1); UPD(1, 2, A1, B2); UPD(1, 3, A1, B3); UPD(1, 4, A1, B4);
                UPD(2, 0, A2, B0); UPD(2, 1, A2, B1); UPD(2, 2, A2, B2); UPD(2, 3, A2, B3); UPD(2, 4, A2, B4);
                UPD(3, 0, A3, B0); UPD(3, 1, A3, B1); UPD(3, 2, A3, B2); UPD(3, 3, A3, B3); UPD(3, 4, A3, B4);
                UPD(4, 0, A4, B0); UPD(4, 1, A4, B1); UPD(4, 2, A4, B2); UPD(4, 3, A4, B3); UPD(4, 4, A4, B4);
#undef UPD
            }
        }
    } else {
        // fallback: direct (uncoalesced) msa reads
        for (int k = 0; k < 8; ++k) {
            const int s = tid + (k << 8);
            const int* rp = msa + (size_t)s * SEQ_LEN;
            const int A0 = rp[i0 + 0] * NS, A1 = rp[i0 + 1] * NS, A2 = rp[i0 + 2] * NS,
                      A3 = rp[i0 + 3] * NS, A4 = rp[i0 + 4] * NS;
            const int B0 = rp[j0 + 0], B1 = rp[j0 + 1], B2 = rp[j0 + 2],
                      B3 = rp[j0 + 3], B4 = rp[j0 + 4];
#define UPD(PI, PJ, AA, BB) atomicAdd(&h_s[(PI * G + PJ) * HB + AA + BB], 1)
            UPD(0, 0, A0, B0); UPD(0, 1, A0, B1); UPD(0, 2, A0, B2); UPD(0, 3, A0, B3); UPD(0, 4, A0, B4);
            UPD(1, 0, A1, B0); UPD(1, 1, A1, B1); UPD(1, 2, A1, B2); UPD(1, 3, A1, B3); UPD(1, 4, A1, B4);
            UPD(2, 0, A2, B0); UPD(2, 1, A2, B1); UPD(2, 2, A2, B2); UPD(2, 3, A2, B3); UPD(2, 4, A2, B4);
            UPD(3, 0, A3, B0); UPD(3, 1, A3, B1); UPD(3, 2, A3, B2); UPD(3, 3, A3, B3); UPD(3, 4, A3, B4);
            UPD(4, 0, A4, B0); UPD(4, 1, A4, B1); UPD(4, 2, A4, B2); UPD(4, 3, A4, B3); UPD(4, 4, A4, B4);
#undef UPD
        }
    }
    __syncthreads();

    // finish: wave w handles pairs p = w, w+4, ...
    for (int p = w; p < G * G; p += 4) {
        const int pi = p / G, pj = p - (p / G) * G;
        if (diag && pi >= pj) continue;    // wave-uniform
        const int* h = h_s + p * HB;

        float mterm = 0.f, tpart = 0.f;
        if (lane < NAA) {
            int s = 0;
#pragma unroll
            for (int b = 0; b < NAA; ++b) s += h[lane * NS + b];
            const float R = (float)s;
            tpart = R;
            if (s > 0) mterm = R * __log2f(R);
        } else if (lane >= 32 && lane < 32 + NAA) {
            const int c = lane - 32;
            int s = 0;
#pragma unroll
            for (int a = 0; a < NAA; ++a) s += h[a * NS + c];
            const float C = (float)s;
            if (s > 0) mterm = C * __log2f(C);
        }

        float part = -mterm;    // accumulates SumJlgJ - SumRalgRa - SumCblgCb
#pragma unroll
        for (int u = 0; u < 7; ++u) {
            const int k2 = lane + (u << 6);
            if (k2 < NAA * NAA) {
                const int row = k2 / NAA;
                const int col = k2 - row * NAA;
                const int J = h[row * NS + col];
                if (J > 0) {
                    const float fJ = (float)J;
                    part += fJ * __log2f(fJ);
                }
            }
        }
#pragma unroll
        for (int o = 32; o; o >>= 1) {
            part += __shfl_down(part, o, 64);
            tpart += __shfl_down(tpart, o, 64);
        }
        if (lane == 0) {
            const float m = (tpart > 0.f)
                                ? __fdividef(part, tpart) + __log2f(tpart)
                                : 0.f;
            mi[(size_t)(i0 + pi) * SEQ_LEN + (j0 + pj)] = m;
            mi[(size_t)(j0 + pj) * SEQ_LEN + (i0 + pi)] = m;
        }
    }
}

// ---------------------------------------------------------------------------
extern "C" void kernel_launch(void* const* d_in, const int* in_sizes, int n_in,
                              void* d_out, int out_size, void* d_ws, size_t ws_size,
                              hipStream_t stream) {
    const int* msa = (const int*)d_in[0];
    const float* pc = (const float*)d_in[1];

    float* pssm = (float*)d_out;         // 512*20
    float* cons = pssm + SEQ_LEN * NAA;  // 512
    float* mi = cons + SEQ_LEN;          // 512*512

    unsigned char* cols = (unsigned char*)d_ws;  // 100*2048 = 200 KB
    const int do_pack = (ws_size >= (size_t)MPOS * N_SEQS) ? 1 : 0;

    pos_kernel<<<POSB, 256, 0, stream>>>(msa, pc, cols, do_pack, pssm, cons, mi);
    mi_kernel<<<NTILE, 256, 0, stream>>>(msa, cols, do_pack, mi);
}

// Round 7
// 17.940 us; speedup vs baseline: 1.3678x; 1.3678x over previous
//
#include <hip/hip_runtime.h>

#define N_SEQS 2048
#define SEQ_LEN 512
#define NAA 20
#define NS 21                  // states incl. gap (pad bin)
#define MPOS 100
#define G 4                    // tile side
#define NG 25                  // MPOS / G
#define NTILE 325              // NG*(NG+1)/2 tile-pairs (ti<=tj)
#define HB (NS * NS)           // 441
#define POSB 64                // pos blocks (8 positions each)
#define NBLK (NTILE + POSB)    // 389

// ---------------------------------------------------------------------------
// Single fused kernel, 512 threads/block.
//  blocks [0, NTILE): MI 4x4 tile-pairs. 2-way seq split: waves 0-3 build
//    histogram copy A (seqs 0-1023), waves 4-7 copy B (seqs 1024-2047).
//  blocks [NTILE, NBLK): 8 positions each -> pssm, conservation, MI zeroing.
// ---------------------------------------------------------------------------
__global__ __launch_bounds__(512) void fused_kernel(const int* __restrict__ msa,
                                                    const float* __restrict__ pc,
                                                    float* __restrict__ pssm,
                                                    float* __restrict__ cons,
                                                    float* __restrict__ mi) {
    __shared__ int h_s[2 * 16 * HB];   // 14112 ints = 56448 B

    const int tid = threadIdx.x;
    const int w = tid >> 6;
    const int lane = tid & 63;
    const int bid = blockIdx.x;

    if (bid < NTILE) {
        // ======================== MI tile-pair part ========================
        int t = bid, ti = 0, off = 0;
        while (off + (NG - ti) <= t) { off += NG - ti; ++ti; }
        const int tj = ti + (t - off);
        const int i0 = ti * G, j0 = tj * G;
        const bool diag = (ti == tj);

        for (int k = tid; k < 2 * 16 * HB; k += 512) h_s[k] = 0;
        __syncthreads();

        const int half = tid >> 8;      // 0 or 1 (waves 0-3 vs 4-7)
        const int htid = tid & 255;
        int* H = h_s + half * (16 * HB);
#pragma unroll
        for (int k = 0; k < 4; ++k) {
            const int s = half * 1024 + htid + (k << 8);
            const int* rp = msa + (size_t)s * SEQ_LEN;
            const int4 va = *(const int4*)(rp + i0);
            const int4 vb = *(const int4*)(rp + j0);
            const int A0 = va.x * NS, A1 = va.y * NS, A2 = va.z * NS, A3 = va.w * NS;
#define UPD(PI, PJ, AA, BB) atomicAdd(&H[(PI * 4 + PJ) * HB + AA + BB], 1)
            UPD(0, 0, A0, vb.x); UPD(0, 1, A0, vb.y); UPD(0, 2, A0, vb.z); UPD(0, 3, A0, vb.w);
            UPD(1, 0, A1, vb.x); UPD(1, 1, A1, vb.y); UPD(1, 2, A1, vb.z); UPD(1, 3, A1, vb.w);
            UPD(2, 0, A2, vb.x); UPD(2, 1, A2, vb.y); UPD(2, 2, A2, vb.z); UPD(2, 3, A2, vb.w);
            UPD(3, 0, A3, vb.x); UPD(3, 1, A3, vb.y); UPD(3, 2, A3, vb.z); UPD(3, 3, A3, vb.w);
#undef UPD
        }
        __syncthreads();

        // finish: wave w handles pairs 2w and 2w+1 (16 pairs over 8 waves)
#pragma unroll
        for (int q = 0; q < 2; ++q) {
            const int p = w * 2 + q;
            const int pi = p >> 2, pj = p & 3;
            if (diag && pi >= pj) continue;       // wave-uniform skip
            const int* hA = h_s + p * HB;
            const int* hB = h_s + 16 * HB + p * HB;

            float mterm = 0.f, tpart = 0.f;
            if (lane < NAA) {
                int s = 0;
#pragma unroll
                for (int b = 0; b < NAA; ++b)
                    s += hA[lane * NS + b] + hB[lane * NS + b];
                if (s > 0) {
                    const float R = (float)s;
                    tpart = R;
                    mterm = R * __log2f(R);
                }
            } else if (lane >= 32 && lane < 32 + NAA) {
                const int c = lane - 32;
                int s = 0;
#pragma unroll
                for (int a = 0; a < NAA; ++a)
                    s += hA[a * NS + c] + hB[a * NS + c];
                if (s > 0) {
                    const float C = (float)s;
                    mterm = C * __log2f(C);
                }
            }

            float part = -mterm;   // Sum J lgJ - Sum Ra lgRa - Sum Cb lgCb
#pragma unroll
            for (int u = 0; u < 7; ++u) {
                const int k2 = lane + (u << 6);
                if (k2 < NAA * NAA) {
                    const int row = k2 / NAA;
                    const int col = k2 - row * NAA;
                    const int J = hA[row * NS + col] + hB[row * NS + col];
                    if (J > 0) {
                        const float fJ = (float)J;
                        part += fJ * __log2f(fJ);
                    }
                }
            }
#pragma unroll
            for (int o = 32; o; o >>= 1) {
                part += __shfl_down(part, o, 64);
                tpart += __shfl_down(tpart, o, 64);
            }
            if (lane == 0) {
                const float m = (tpart > 0.f)
                                    ? __fdividef(part, tpart) + __log2f(tpart)
                                    : 0.f;
                mi[(size_t)(i0 + pi) * SEQ_LEN + (j0 + pj)] = m;
                mi[(size_t)(j0 + pj) * SEQ_LEN + (i0 + pi)] = m;
            }
        }
    } else {
        // ========================== position part ==========================
        const int pb = bid - NTILE;      // 0..63
        const int i0 = pb * 8;

        // zero MI rows i0..i0+7 (race-free: MI blocks own off-diag [0,100)^2)
        for (int r = 0; r < 8; ++r) {
            const int i = i0 + r;
            float* rowp = mi + (size_t)i * SEQ_LEN;
            if (i < MPOS) {
                const int c = MPOS + tid;
                if (c < SEQ_LEN) rowp[c] = 0.f;
                if (tid == 0) rowp[i] = 0.f;
            } else {
                if (tid < SEQ_LEN / 4)
                    ((float4*)rowp)[tid] = make_float4(0.f, 0.f, 0.f, 0.f);
            }
        }

        // per-wave 8x21 histograms: h_s[w*168 + p*21 + a]
        for (int k = tid; k < 8 * 8 * NS; k += 512) h_s[k] = 0;
        __syncthreads();

        int* h = h_s + w * (8 * NS);
#pragma unroll
        for (int k = 0; k < 4; ++k) {
            const int s = tid + (k << 9);
            const int* rp = msa + (size_t)s * SEQ_LEN + i0;
            const int4 v0 = *(const int4*)rp;
            const int4 v1 = *(const int4*)(rp + 4);
            atomicAdd(&h[0 * NS + v0.x], 1);
            atomicAdd(&h[1 * NS + v0.y], 1);
            atomicAdd(&h[2 * NS + v0.z], 1);
            atomicAdd(&h[3 * NS + v0.w], 1);
            atomicAdd(&h[4 * NS + v1.x], 1);
            atomicAdd(&h[5 * NS + v1.y], 1);
            atomicAdd(&h[6 * NS + v1.z], 1);
            atomicAdd(&h[7 * NS + v1.w], 1);
        }
        __syncthreads();

        float* cntf = (float*)(h_s + 2048);   // beyond the 1344 used ints
        if (tid < 8 * NAA) {
            const int p = tid / NAA, a = tid - p * NAA;
            const int idx = p * NS + a;
            int c = 0;
#pragma unroll
            for (int ww = 0; ww < 8; ++ww) c += h_s[ww * (8 * NS) + idx];
            cntf[tid] = (float)c;
            const float pcnt = 0.01f * pc[0];
            const float freq = __fdividef((float)c + pcnt, 2048.0f + pcnt * 20.0f);
            pssm[(size_t)(i0 + p) * NAA + a] = __logf(freq * 20.0f + 1e-10f);
        }
        __syncthreads();

        // conservation: 8 groups of 32 threads (waves 0-3)
        if (tid < 256) {
            const int p = tid >> 5, l = tid & 31;
            const float fc = (l < NAA) ? cntf[p * NAA + l] : 0.f;
            float tt = fc;
#pragma unroll
            for (int o = 16; o; o >>= 1) tt += __shfl_xor(tt, o, 32);
            const float ts2 = fmaxf(tt, 1.f);
            const float f = __fdividef(fc, ts2);
            float term = (l < NAA) ? -f * __log2f(f + 1e-10f) : 0.f;
#pragma unroll
            for (int o = 16; o; o >>= 1) term += __shfl_xor(term, o, 32);
            if (l == 0)
                cons[i0 + p] = (tt > 0.f) ? (1.f - term * 0.2313782131597592f) : 0.f;
        }
    }
}

// ---------------------------------------------------------------------------
extern "C" void kernel_launch(void* const* d_in, const int* in_sizes, int n_in,
                              void* d_out, int out_size, void* d_ws, size_t ws_size,
                              hipStream_t stream) {
    const int* msa = (const int*)d_in[0];
    const float* pc = (const float*)d_in[1];

    float* pssm = (float*)d_out;         // 512*20
    float* cons = pssm + SEQ_LEN * NAA;  // 512
    float* mi = cons + SEQ_LEN;          // 512*512

    fused_kernel<<<NBLK, 512, 0, stream>>>(msa, pc, pssm, cons, mi);
}